// Round 1
// baseline (1454.469 us; speedup 1.0000x reference)
//
#include <hip/hip_runtime.h>
#include <math.h>

#define TOK   4096
#define HD    1024
#define NEXP  16
#define CAPM  768

// d_out float offsets (return order: dispatch, combine, router_probs, aux, importance)
static const size_t DISP_OFF = 0;
static const size_t COMB_OFF = 50331648;   // TOK*NEXP*CAPM
static const size_t RP_OFF   = 100663296;
static const size_t AUX_OFF  = 100728832;
static const size_t IMP_OFF  = 100728833;

// ws float offsets
#define WS_IMPZ   0        // [4096]  atomic accum (zeroed)
#define WS_COLSUM 4096     // [1024]  atomic accum (zeroed)
#define WS_T1PRE  5120     // [256]   atomic accum (zeroed)
#define WS_PROBS  5376     // [16]    atomic accum (zeroed)
#define WS_AK     5392     // [1] int adaptive_k
#define WS_TOPKP  5400     // [8192]
#define WS_TOPKI  13592    // [8192] int
#define WS_ZEROF  5400     // floats to zero at start

// ---------------------------------------------------------------------------
// Fused GEMM: C = relu(x @ [W1 | Wi1] + [b1 | bi1]); W1 columns -> h1 scratch,
// Wi1 columns -> dot with Wi2 and atomicAdd into impz (importance pre-act).
// Tile 128x128, 8x8 micro (split 4+4 fragments for conflict-free ds_read_b128),
// double-buffered LDS, K-tile 16. grid = (12 n-tiles, 32 m-tiles).
// ---------------------------------------------------------------------------
__global__ __launch_bounds__(256, 2) void kA(
    const float* __restrict__ x, const float* __restrict__ W1,
    const float* __restrict__ b1, const float* __restrict__ Wi1,
    const float* __restrict__ bi1, const float* __restrict__ Wi2,
    float* __restrict__ h1out, float* __restrict__ impz)
{
    __shared__ __align__(16) float As[2][16][132];  // padded, transposed: As[k][m]
    __shared__ __align__(16) float Bs[2][16][128];  // Bs[k][n]
    __shared__ float red[128];

    const int tid = threadIdx.x;
    const int tx = tid & 15;
    const int ty = tid >> 4;
    const int n0 = blockIdx.x * 128;   // 0..1535 (>=1024 -> Wi1 branch)
    const int m0 = blockIdx.y * 128;
    const bool isW1 = (n0 < HD);
    const float* __restrict__ Bp = isW1 ? (W1 + n0) : (Wi1 + (n0 - HD));
    const int ldb = isW1 ? 1024 : 512;

    float acc[8][8];
#pragma unroll
    for (int i = 0; i < 8; ++i)
#pragma unroll
        for (int j = 0; j < 8; ++j) acc[i][j] = 0.f;

    float4 aR[2], bR[2];

    // prologue: stage k-tile 0
#pragma unroll
    for (int i = 0; i < 2; ++i) {
        const int s = tid + i * 256;
        const int m = s >> 2, kq = s & 3;
        aR[i] = *(const float4*)(x + (size_t)(m0 + m) * HD + kq * 4);
        const int kk = s >> 5, nq = s & 31;
        bR[i] = *(const float4*)(Bp + (size_t)kk * ldb + nq * 4);
    }
#pragma unroll
    for (int i = 0; i < 2; ++i) {
        const int s = tid + i * 256;
        const int m = s >> 2, kq = s & 3;
        As[0][kq * 4 + 0][m] = aR[i].x;
        As[0][kq * 4 + 1][m] = aR[i].y;
        As[0][kq * 4 + 2][m] = aR[i].z;
        As[0][kq * 4 + 3][m] = aR[i].w;
        const int kk = s >> 5, nq = s & 31;
        *(float4*)&Bs[0][kk][nq * 4] = bR[i];
    }
    __syncthreads();

    for (int kt = 0; kt < 64; ++kt) {
        const int buf = kt & 1;
        if (kt < 63) {
#pragma unroll
            for (int i = 0; i < 2; ++i) {
                const int s = tid + i * 256;
                const int m = s >> 2, kq = s & 3;
                aR[i] = *(const float4*)(x + (size_t)(m0 + m) * HD + (kt + 1) * 16 + kq * 4);
                const int kk = s >> 5, nq = s & 31;
                bR[i] = *(const float4*)(Bp + (size_t)((kt + 1) * 16 + kk) * ldb + nq * 4);
            }
        }
#pragma unroll
        for (int kk = 0; kk < 16; ++kk) {
            float4 a0  = *(const float4*)&As[buf][kk][ty * 4];
            float4 a1  = *(const float4*)&As[buf][kk][ty * 4 + 64];
            float4 b0  = *(const float4*)&Bs[buf][kk][tx * 4];
            float4 b1v = *(const float4*)&Bs[buf][kk][tx * 4 + 64];
            float av[8] = { a0.x, a0.y, a0.z, a0.w, a1.x, a1.y, a1.z, a1.w };
            float bv[8] = { b0.x, b0.y, b0.z, b0.w, b1v.x, b1v.y, b1v.z, b1v.w };
#pragma unroll
            for (int i = 0; i < 8; ++i)
#pragma unroll
                for (int j = 0; j < 8; ++j)
                    acc[i][j] = fmaf(av[i], bv[j], acc[i][j]);
        }
        if (kt < 63) {
            const int nb = buf ^ 1;
            // safe: nb was last read in compute(kt-1), barriered at end of kt-1
#pragma unroll
            for (int i = 0; i < 2; ++i) {
                const int s = tid + i * 256;
                const int m = s >> 2, kq = s & 3;
                As[nb][kq * 4 + 0][m] = aR[i].x;
                As[nb][kq * 4 + 1][m] = aR[i].y;
                As[nb][kq * 4 + 2][m] = aR[i].z;
                As[nb][kq * 4 + 3][m] = aR[i].w;
                const int kk = s >> 5, nq = s & 31;
                *(float4*)&Bs[nb][kk][nq * 4] = bR[i];
            }
            __syncthreads();
        }
    }

    if (isW1) {
        float4 bb0 = *(const float4*)(b1 + n0 + tx * 4);
        float4 bb1 = *(const float4*)(b1 + n0 + tx * 4 + 64);
        const float bvv[8] = { bb0.x, bb0.y, bb0.z, bb0.w, bb1.x, bb1.y, bb1.z, bb1.w };
#pragma unroll
        for (int i = 0; i < 8; ++i) {
            const int m = m0 + ty * 4 + ((i < 4) ? i : (60 + i));
            float4 o0, o1;
            o0.x = fmaxf(acc[i][0] + bvv[0], 0.f);
            o0.y = fmaxf(acc[i][1] + bvv[1], 0.f);
            o0.z = fmaxf(acc[i][2] + bvv[2], 0.f);
            o0.w = fmaxf(acc[i][3] + bvv[3], 0.f);
            o1.x = fmaxf(acc[i][4] + bvv[4], 0.f);
            o1.y = fmaxf(acc[i][5] + bvv[5], 0.f);
            o1.z = fmaxf(acc[i][6] + bvv[6], 0.f);
            o1.w = fmaxf(acc[i][7] + bvv[7], 0.f);
            *(float4*)(h1out + (size_t)m * HD + n0 + tx * 4) = o0;
            *(float4*)(h1out + (size_t)m * HD + n0 + tx * 4 + 64) = o1;
        }
    } else {
        const int nW = n0 - HD;
        float4 bb0 = *(const float4*)(bi1 + nW + tx * 4);
        float4 bb1 = *(const float4*)(bi1 + nW + tx * 4 + 64);
        float4 w0  = *(const float4*)(Wi2 + nW + tx * 4);
        float4 w1  = *(const float4*)(Wi2 + nW + tx * 4 + 64);
        const float bvv[8] = { bb0.x, bb0.y, bb0.z, bb0.w, bb1.x, bb1.y, bb1.z, bb1.w };
        const float wvv[8] = { w0.x, w0.y, w0.z, w0.w, w1.x, w1.y, w1.z, w1.w };
        if (tid < 128) red[tid] = 0.f;
        __syncthreads();
#pragma unroll
        for (int i = 0; i < 8; ++i) {
            const int ml = ty * 4 + ((i < 4) ? i : (60 + i));
            float s = 0.f;
#pragma unroll
            for (int j = 0; j < 8; ++j)
                s += fmaxf(acc[i][j] + bvv[j], 0.f) * wvv[j];
            atomicAdd(&red[ml], s);
        }
        __syncthreads();
        if (tid < 128) atomicAdd(&impz[m0 + tid], red[tid]);
    }
}

// importance = sigmoid(z + bi2)
__global__ void kSig(const float* __restrict__ impz, const float* __restrict__ bi2,
                     float* __restrict__ impOut)
{
    const int t = blockIdx.x * 256 + threadIdx.x;
    const float z = impz[t] + bi2[0];
    impOut[t] = 1.f / (1.f + expf(-z));   // precise expf: iw threshold at 0.5 is flip-sensitive
}

// column sums of x -> colsum (for avg_feat)
__global__ void kAvg(const float* __restrict__ x, float* __restrict__ colsum)
{
    const int c = blockIdx.x * 256 + threadIdx.x;
    const int r0 = blockIdx.y * 64;
    float s = 0.f;
    for (int r = r0; r < r0 + 64; ++r) s += x[(size_t)r * HD + c];
    atomicAdd(&colsum[c], s);
}

// t1pre[j] += sum_{i in chunk} avg_feat[i] * Wt1[i][j]   (rows 0..1023)
__global__ void kTk1(const float* __restrict__ colsum, const float* __restrict__ Wt1,
                     float* __restrict__ t1pre)
{
    const int j = threadIdx.x;
    const int i0 = blockIdx.x * 32;
    float s = 0.f;
    for (int i = i0; i < i0 + 32; ++i)
        s = fmaf(colsum[i] * (1.f / TOK), Wt1[i * 256 + j], s);
    atomicAdd(&t1pre[j], s);
}

// finish top_k predictor: imp_mean term, relu, @Wt2 + bt2, argmax -> adaptive_k
__global__ void kTk2(const float* __restrict__ imp, const float* __restrict__ t1pre,
                     const float* __restrict__ Wt1, const float* __restrict__ bt1,
                     const float* __restrict__ Wt2, const float* __restrict__ bt2,
                     int* __restrict__ akOut)
{
    __shared__ float sm[256];
    const int tid = threadIdx.x;
    float s = 0.f;
    for (int i = 0; i < 16; ++i) s += imp[tid + i * 256];
    sm[tid] = s;
    __syncthreads();
    for (int off = 128; off > 0; off >>= 1) {
        if (tid < off) sm[tid] += sm[tid + off];
        __syncthreads();
    }
    const float imp_mean = sm[0] * (1.f / TOK);
    __syncthreads();
    const float t1 = fmaxf(t1pre[tid] + imp_mean * Wt1[1024 * 256 + tid] + bt1[tid], 0.f);
    sm[tid] = t1 * Wt2[tid * 2 + 0];
    __syncthreads();
    for (int off = 128; off > 0; off >>= 1) {
        if (tid < off) sm[tid] += sm[tid + off];
        __syncthreads();
    }
    const float l0 = sm[0] + bt2[0];
    __syncthreads();
    sm[tid] = t1 * Wt2[tid * 2 + 1];
    __syncthreads();
    for (int off = 128; off > 0; off >>= 1) {
        if (tid < off) sm[tid] += sm[tid + off];
        __syncthreads();
    }
    const float l1 = sm[0] + bt2[1];
    if (tid == 0) akOut[0] = (l1 > l0) ? 2 : 1;  // softmax monotone; argmax tie -> idx 0
}

// logits = h1 @ W2 + b2; softmax; router_probs out; stable top-2; probsum atomics.
// 64 tokens/block, 4 k-quarter threads per token; W2 via wave-uniform s_loads.
__global__ __launch_bounds__(256) void kLog(
    const float* __restrict__ h1, const float* __restrict__ W2,
    const float* __restrict__ b2, float* __restrict__ rp,
    float* __restrict__ topkP, int* __restrict__ topkI,
    float* __restrict__ probsum)
{
    __shared__ float acc4[4][64][16];
    __shared__ float ps[16];
    const int tid = threadIdx.x;
    const int m = tid & 63;
    const int q = __builtin_amdgcn_readfirstlane(tid >> 6);  // wave-uniform
    const int t0 = blockIdx.x * 64;
    const float* __restrict__ hrow = h1 + (size_t)(t0 + m) * HD + q * 256;
    const float* __restrict__ wq = W2 + q * 256 * NEXP;
    float a[16];
#pragma unroll
    for (int e = 0; e < 16; ++e) a[e] = 0.f;
    for (int kc = 0; kc < 256; kc += 4) {
        float4 h = *(const float4*)(hrow + kc);
        const float* wr = wq + kc * NEXP;
#pragma unroll
        for (int e = 0; e < 16; ++e) {
            float v = a[e];
            v = fmaf(h.x, wr[e], v);
            v = fmaf(h.y, wr[16 + e], v);
            v = fmaf(h.z, wr[32 + e], v);
            v = fmaf(h.w, wr[48 + e], v);
            a[e] = v;
        }
    }
#pragma unroll
    for (int e = 0; e < 16; ++e) acc4[q][m][e] = a[e];
    if (tid < 16) ps[tid] = 0.f;
    __syncthreads();
    if (tid < 64) {
        float p[16];
        float mx = -1e30f;
#pragma unroll
        for (int e = 0; e < 16; ++e) {
            const float lg = acc4[0][m][e] + acc4[1][m][e] + acc4[2][m][e] + acc4[3][m][e] + b2[e];
            p[e] = lg;
            mx = fmaxf(mx, lg);
        }
        float sum = 0.f;
#pragma unroll
        for (int e = 0; e < 16; ++e) { p[e] = expf(p[e] - mx); sum += p[e]; }
        const float inv = 1.f / sum;
#pragma unroll
        for (int e = 0; e < 16; ++e) p[e] *= inv;
        const int t = t0 + m;
        float* rr = rp + (size_t)t * NEXP;
        *(float4*)(rr + 0)  = make_float4(p[0], p[1], p[2], p[3]);
        *(float4*)(rr + 4)  = make_float4(p[4], p[5], p[6], p[7]);
        *(float4*)(rr + 8)  = make_float4(p[8], p[9], p[10], p[11]);
        *(float4*)(rr + 12) = make_float4(p[12], p[13], p[14], p[15]);
        // stable top-2 (strict > keeps lowest index on ties, matching lax.top_k)
        int i0 = 0; float v0 = p[0];
#pragma unroll
        for (int e = 1; e < 16; ++e) if (p[e] > v0) { v0 = p[e]; i0 = e; }
        int i1 = -1; float v1 = -1e30f;
#pragma unroll
        for (int e = 0; e < 16; ++e) if (e != i0 && p[e] > v1) { v1 = p[e]; i1 = e; }
        topkP[t * 2] = v0; topkP[t * 2 + 1] = v1;
        topkI[t * 2] = i0; topkI[t * 2 + 1] = i1;
#pragma unroll
        for (int e = 0; e < 16; ++e) atomicAdd(&ps[e], p[e]);
    }
    __syncthreads();
    if (tid < 16) atomicAdd(&probsum[tid], ps[tid]);
}

// exact sequential per-expert position scan over N=8192 (b,s,k) items + scatter + aux
__global__ __launch_bounds__(256) void kScan(
    const float* __restrict__ topkP, const int* __restrict__ topkI,
    const int* __restrict__ akPtr, const float* __restrict__ probsum,
    const float* __restrict__ imp, float* __restrict__ disp,
    float* __restrict__ comb, float* __restrict__ aux)
{
    __shared__ int cnt[256][16];
    __shared__ int totals[16];
    const int tid = threadIdx.x;
    const int ak = akPtr[0];
    const int cap = 384 * ak;   // floor(4096*1.5*ak/16)
    int c[16];
#pragma unroll
    for (int e = 0; e < 16; ++e) c[e] = 0;
    const int n0 = tid * 32;
    for (int j = 0; j < 32; ++j) {
        const int n = n0 + j;
        if ((n & 1) < ak) c[topkI[n]]++;
    }
#pragma unroll
    for (int e = 0; e < 16; ++e) cnt[tid][e] = c[e];
    __syncthreads();
    if (tid < 16) {   // exclusive scan over the 256 chunks, per expert
        int run = 0;
        for (int i = 0; i < 256; ++i) { const int v = cnt[i][tid]; cnt[i][tid] = run; run += v; }
        totals[tid] = run;
    }
    __syncthreads();
#pragma unroll
    for (int e = 0; e < 16; ++e) c[e] = cnt[tid][e];
    for (int j = 0; j < 32; ++j) {
        const int n = n0 + j;
        const int k = n & 1;
        if (k < ak) {
            const int e = topkI[n];
            const int pos = c[e]++;
            if (pos < cap) {
                const int t = n >> 1;
                const float p0 = topkP[t * 2], p1 = topkP[t * 2 + 1];
                const float ssum = (ak == 2) ? (p0 + p1) : p0;
                const float pv = ((k == 0) ? p0 : p1) / (ssum + 1e-8f);
                const float iw = (imp[t] > 0.5f) ? 2.f : 1.f;
                const size_t idx = (size_t)t * (NEXP * CAPM) + (size_t)e * CAPM + pos;
                disp[idx] = 1.f;
                comb[idx] = pv * iw;
            }
        }
    }
    if (tid == 0) {
        float a = 0.f;
        const float invAk = 1.f / (float)(TOK * ak);
        for (int e = 0; e < 16; ++e)
            a += (probsum[e] * (1.f / TOK)) * ((float)totals[e] * invAk);
        aux[0] = a * (float)NEXP;
    }
}

extern "C" void kernel_launch(void* const* d_in, const int* in_sizes, int n_in,
                              void* d_out, int out_size, void* d_ws, size_t ws_size,
                              hipStream_t stream)
{
    const float* x   = (const float*)d_in[0];
    const float* W1  = (const float*)d_in[1];
    const float* b1  = (const float*)d_in[2];
    const float* W2  = (const float*)d_in[3];
    const float* b2  = (const float*)d_in[4];
    const float* Wi1 = (const float*)d_in[5];
    const float* bi1 = (const float*)d_in[6];
    const float* Wi2 = (const float*)d_in[7];
    const float* bi2 = (const float*)d_in[8];
    const float* Wt1 = (const float*)d_in[9];
    const float* bt1 = (const float*)d_in[10];
    const float* Wt2 = (const float*)d_in[11];
    const float* bt2 = (const float*)d_in[12];
    (void)in_sizes; (void)n_in; (void)out_size; (void)ws_size;

    float* out = (float*)d_out;
    float* wsF = (float*)d_ws;
    int*   akP = (int*)(wsF + WS_AK);

    // zero the atomic accumulators (ws is poisoned each call)
    hipMemsetAsync(d_ws, 0, (size_t)WS_ZEROF * 4, stream);

    // h1 intermediate lives in the dispatch region (zeroed later, before scatter)
    float* h1scratch = out + DISP_OFF;

    kA  <<<dim3(12, 32), 256, 0, stream>>>(x, W1, b1, Wi1, bi1, Wi2,
                                           h1scratch, wsF + WS_IMPZ);
    kSig<<<16, 256, 0, stream>>>(wsF + WS_IMPZ, bi2, out + IMP_OFF);
    kAvg<<<dim3(4, 64), 256, 0, stream>>>(x, wsF + WS_COLSUM);
    kTk1<<<32, 256, 0, stream>>>(wsF + WS_COLSUM, Wt1, wsF + WS_T1PRE);
    kTk2<<<1, 256, 0, stream>>>(out + IMP_OFF, wsF + WS_T1PRE, Wt1, bt1, Wt2, bt2, akP);
    kLog<<<64, 256, 0, stream>>>(h1scratch, W2, b2, out + RP_OFF,
                                 wsF + WS_TOPKP, (int*)(wsF + WS_TOPKI), wsF + WS_PROBS);
    // zero dispatch + combine (402,653,184 bytes) AFTER h1 is consumed
    hipMemsetAsync(out, 0, (size_t)COMB_OFF * 2 * sizeof(float), stream);
    kScan<<<1, 256, 0, stream>>>(wsF + WS_TOPKP, (int*)(wsF + WS_TOPKI), akP,
                                 wsF + WS_PROBS, out + IMP_OFF,
                                 out + DISP_OFF, out + COMB_OFF, out + AUX_OFF);
}

// Round 2
// 656.595 us; speedup vs baseline: 2.2152x; 2.2152x over previous
//
#include <hip/hip_runtime.h>
#include <math.h>

#define TOK   4096
#define HD    1024
#define NEXP  16
#define CAPM  768

// d_out float offsets (return order: dispatch, combine, router_probs, aux, importance)
static const size_t DISP_OFF = 0;
static const size_t COMB_OFF = 50331648;   // TOK*NEXP*CAPM
static const size_t RP_OFF   = 100663296;
static const size_t AUX_OFF  = 100728832;
static const size_t IMP_OFF  = 100728833;

// ws float offsets
#define WS_IMPZ   0        // [4096]  atomic accum (zeroed)
#define WS_COLSUM 4096     // [1024]  atomic accum (zeroed)
#define WS_T1PRE  5120     // [256]   atomic accum (zeroed)
#define WS_PROBS  5376     // [16]    atomic accum (zeroed)
#define WS_AK     5392     // [1] int adaptive_k
#define WS_TOPKP  5400     // [8192]
#define WS_TOPKI  13592    // [8192] int
#define WS_ZEROF  5400     // floats to zero at start

// ---------------------------------------------------------------------------
// Fused GEMM: relu(x @ [W1 | Wi1] + bias); W1 cols -> h1, Wi1 cols -> dot Wi2
// -> impz. Tile 64x128, micro 4x8 (32 acc regs — spill-proof), single LDS
// buffer with loads issued before the barrier, grid 12x64 = 768 = 3/CU exact.
// ---------------------------------------------------------------------------
__global__ __launch_bounds__(256) void kA(
    const float* __restrict__ x, const float* __restrict__ W1,
    const float* __restrict__ b1, const float* __restrict__ Wi1,
    const float* __restrict__ bi1, const float* __restrict__ Wi2,
    float* __restrict__ h1out, float* __restrict__ impz)
{
    __shared__ __align__(16) float As[16][68];   // As[k][m], pad 68 keeps 16B align
    __shared__ __align__(16) float Bs[16][128];  // Bs[k][n]
    __shared__ float red[64];

    const int tid = threadIdx.x;
    const int tx = tid & 15;
    const int ty = tid >> 4;
    const int n0 = blockIdx.x * 128;   // 0..1535 (>=1024 -> Wi1 branch)
    const int m0 = blockIdx.y * 64;
    const bool isW1 = (n0 < HD);
    const float* __restrict__ Bp = isW1 ? (W1 + n0) : (Wi1 + (n0 - HD));
    const int ldb = isW1 ? 1024 : 512;

    const int am = tid >> 2, akq = tid & 3;      // A staging coords
    const int br = tid >> 5, bq = tid & 31;      // B staging coords

    if (tid < 64) red[tid] = 0.f;

    float acc[4][8];
#pragma unroll
    for (int i = 0; i < 4; ++i)
#pragma unroll
        for (int j = 0; j < 8; ++j) acc[i][j] = 0.f;

#pragma unroll 1
    for (int kt = 0; kt < 64; ++kt) {
        // issue global loads BEFORE the barrier; regs die at the LDS store
        const float4 av  = *(const float4*)(x + (size_t)(m0 + am) * HD + kt * 16 + akq * 4);
        const float4 bv0 = *(const float4*)(Bp + (size_t)(kt * 16 + br) * ldb + bq * 4);
        const float4 bv1 = *(const float4*)(Bp + (size_t)(kt * 16 + 8 + br) * ldb + bq * 4);
        __syncthreads();   // previous iteration's compute done reading LDS
        As[akq * 4 + 0][am] = av.x;
        As[akq * 4 + 1][am] = av.y;
        As[akq * 4 + 2][am] = av.z;
        As[akq * 4 + 3][am] = av.w;
        *(float4*)&Bs[br][bq * 4]     = bv0;
        *(float4*)&Bs[8 + br][bq * 4] = bv1;
        __syncthreads();
#pragma unroll 4
        for (int kk = 0; kk < 16; ++kk) {
            const float4 a   = *(const float4*)&As[kk][ty * 4];
            const float4 b0  = *(const float4*)&Bs[kk][tx * 4];
            const float4 b1v = *(const float4*)&Bs[kk][tx * 4 + 64];
            const float avv[4] = { a.x, a.y, a.z, a.w };
            const float bvv[8] = { b0.x, b0.y, b0.z, b0.w, b1v.x, b1v.y, b1v.z, b1v.w };
#pragma unroll
            for (int i = 0; i < 4; ++i)
#pragma unroll
                for (int j = 0; j < 8; ++j)
                    acc[i][j] = fmaf(avv[i], bvv[j], acc[i][j]);
        }
    }

    if (isW1) {
        const float4 bb0 = *(const float4*)(b1 + n0 + tx * 4);
        const float4 bb1 = *(const float4*)(b1 + n0 + tx * 4 + 64);
        const float bvv[8] = { bb0.x, bb0.y, bb0.z, bb0.w, bb1.x, bb1.y, bb1.z, bb1.w };
#pragma unroll
        for (int i = 0; i < 4; ++i) {
            const int m = m0 + ty * 4 + i;
            float4 o0, o1;
            o0.x = fmaxf(acc[i][0] + bvv[0], 0.f);
            o0.y = fmaxf(acc[i][1] + bvv[1], 0.f);
            o0.z = fmaxf(acc[i][2] + bvv[2], 0.f);
            o0.w = fmaxf(acc[i][3] + bvv[3], 0.f);
            o1.x = fmaxf(acc[i][4] + bvv[4], 0.f);
            o1.y = fmaxf(acc[i][5] + bvv[5], 0.f);
            o1.z = fmaxf(acc[i][6] + bvv[6], 0.f);
            o1.w = fmaxf(acc[i][7] + bvv[7], 0.f);
            *(float4*)(h1out + (size_t)m * HD + n0 + tx * 4)      = o0;
            *(float4*)(h1out + (size_t)m * HD + n0 + tx * 4 + 64) = o1;
        }
    } else {
        const int nW = n0 - HD;
        const float4 bb0 = *(const float4*)(bi1 + nW + tx * 4);
        const float4 bb1 = *(const float4*)(bi1 + nW + tx * 4 + 64);
        const float4 w0  = *(const float4*)(Wi2 + nW + tx * 4);
        const float4 w1  = *(const float4*)(Wi2 + nW + tx * 4 + 64);
        const float bvv[8] = { bb0.x, bb0.y, bb0.z, bb0.w, bb1.x, bb1.y, bb1.z, bb1.w };
        const float wvv[8] = { w0.x, w0.y, w0.z, w0.w, w1.x, w1.y, w1.z, w1.w };
        __syncthreads();   // red[] zero + last LDS reads done
#pragma unroll
        for (int i = 0; i < 4; ++i) {
            float s = 0.f;
#pragma unroll
            for (int j = 0; j < 8; ++j)
                s += fmaxf(acc[i][j] + bvv[j], 0.f) * wvv[j];
            atomicAdd(&red[ty * 4 + i], s);
        }
        __syncthreads();
        if (tid < 64) atomicAdd(&impz[m0 + tid], red[tid]);
    }
}

// importance = sigmoid(z + bi2)
__global__ void kSig(const float* __restrict__ impz, const float* __restrict__ bi2,
                     float* __restrict__ impOut)
{
    const int t = blockIdx.x * 256 + threadIdx.x;
    const float z = impz[t] + bi2[0];
    impOut[t] = 1.f / (1.f + expf(-z));   // precise expf: iw threshold at 0.5 is flip-sensitive
}

// column sums of x -> colsum (for avg_feat)
__global__ void kAvg(const float* __restrict__ x, float* __restrict__ colsum)
{
    const int c = blockIdx.x * 256 + threadIdx.x;
    const int r0 = blockIdx.y * 64;
    float s = 0.f;
    for (int r = r0; r < r0 + 64; ++r) s += x[(size_t)r * HD + c];
    atomicAdd(&colsum[c], s);
}

// t1pre[j] += sum_{i in chunk} avg_feat[i] * Wt1[i][j]   (rows 0..1023)
__global__ void kTk1(const float* __restrict__ colsum, const float* __restrict__ Wt1,
                     float* __restrict__ t1pre)
{
    const int j = threadIdx.x;
    const int i0 = blockIdx.x * 32;
    float s = 0.f;
    for (int i = i0; i < i0 + 32; ++i)
        s = fmaf(colsum[i] * (1.f / TOK), Wt1[i * 256 + j], s);
    atomicAdd(&t1pre[j], s);
}

// finish top_k predictor: imp_mean term, relu, @Wt2 + bt2, argmax -> adaptive_k
__global__ void kTk2(const float* __restrict__ imp, const float* __restrict__ t1pre,
                     const float* __restrict__ Wt1, const float* __restrict__ bt1,
                     const float* __restrict__ Wt2, const float* __restrict__ bt2,
                     int* __restrict__ akOut)
{
    __shared__ float sm[256];
    const int tid = threadIdx.x;
    float s = 0.f;
    for (int i = 0; i < 16; ++i) s += imp[tid + i * 256];
    sm[tid] = s;
    __syncthreads();
    for (int off = 128; off > 0; off >>= 1) {
        if (tid < off) sm[tid] += sm[tid + off];
        __syncthreads();
    }
    const float imp_mean = sm[0] * (1.f / TOK);
    __syncthreads();
    const float t1 = fmaxf(t1pre[tid] + imp_mean * Wt1[1024 * 256 + tid] + bt1[tid], 0.f);
    sm[tid] = t1 * Wt2[tid * 2 + 0];
    __syncthreads();
    for (int off = 128; off > 0; off >>= 1) {
        if (tid < off) sm[tid] += sm[tid + off];
        __syncthreads();
    }
    const float l0 = sm[0] + bt2[0];
    __syncthreads();
    sm[tid] = t1 * Wt2[tid * 2 + 1];
    __syncthreads();
    for (int off = 128; off > 0; off >>= 1) {
        if (tid < off) sm[tid] += sm[tid + off];
        __syncthreads();
    }
    const float l1 = sm[0] + bt2[1];
    if (tid == 0) akOut[0] = (l1 > l0) ? 2 : 1;  // softmax monotone; argmax tie -> idx 0
}

// logits = h1 @ W2 + b2; softmax; router_probs; stable top-2; probsum.
// 16 tokens x 16 experts per 256-thread block; grid 256 (1 block/CU).
__global__ __launch_bounds__(256) void kLog(
    const float* __restrict__ h1, const float* __restrict__ W2,
    const float* __restrict__ b2, float* __restrict__ rp,
    float* __restrict__ topkP, int* __restrict__ topkI,
    float* __restrict__ probsum)
{
    __shared__ float lg[16][17];
    __shared__ float ex[16][17];
    __shared__ float ps[16];
    const int tid = threadIdx.x;
    const int e  = tid & 15;
    const int tt = tid >> 4;
    const int t  = blockIdx.x * 16 + tt;
    const float* __restrict__ hrow = h1 + (size_t)t * HD;
    float s0 = 0.f, s1 = 0.f, s2 = 0.f, s3 = 0.f;
#pragma unroll 4
    for (int k = 0; k < HD; k += 4) {
        const float4 h = *(const float4*)(hrow + k);
        s0 = fmaf(h.x, W2[(k + 0) * NEXP + e], s0);
        s1 = fmaf(h.y, W2[(k + 1) * NEXP + e], s1);
        s2 = fmaf(h.z, W2[(k + 2) * NEXP + e], s2);
        s3 = fmaf(h.w, W2[(k + 3) * NEXP + e], s3);
    }
    const float logit = (s0 + s1) + (s2 + s3) + b2[e];
    lg[tt][e] = logit;
    if (tid < 16) ps[tid] = 0.f;
    __syncthreads();
    float mx = -1e30f;
#pragma unroll
    for (int j = 0; j < 16; ++j) mx = fmaxf(mx, lg[tt][j]);
    const float my_ex = expf(logit - mx);
    ex[tt][e] = my_ex;
    __syncthreads();
    float sum = 0.f;
#pragma unroll
    for (int j = 0; j < 16; ++j) sum += ex[tt][j];
    const float p = my_ex / sum;
    rp[(size_t)t * NEXP + e] = p;          // coalesced
    lg[tt][e] = p;                          // reuse as prob row
    atomicAdd(&ps[e], p);
    __syncthreads();
    if (e == 0) {
        // stable top-2 (strict > keeps lowest index on ties, matching lax.top_k)
        float pv[16];
#pragma unroll
        for (int j = 0; j < 16; ++j) pv[j] = lg[tt][j];
        int i0 = 0; float v0 = pv[0];
#pragma unroll
        for (int j = 1; j < 16; ++j) if (pv[j] > v0) { v0 = pv[j]; i0 = j; }
        int i1 = -1; float v1 = -1e30f;
#pragma unroll
        for (int j = 0; j < 16; ++j) if (j != i0 && pv[j] > v1) { v1 = pv[j]; i1 = j; }
        topkP[t * 2] = v0; topkP[t * 2 + 1] = v1;
        topkI[t * 2] = i0; topkI[t * 2 + 1] = i1;
    }
    if (tid < 16) atomicAdd(&probsum[tid], ps[tid]);
}

// exact sequential per-expert position scan over N=8192 (b,s,k) items + scatter + aux
__global__ __launch_bounds__(256) void kScan(
    const float* __restrict__ topkP, const int* __restrict__ topkI,
    const int* __restrict__ akPtr, const float* __restrict__ probsum,
    const float* __restrict__ imp, float* __restrict__ disp,
    float* __restrict__ comb, float* __restrict__ aux)
{
    __shared__ int cnt[256][16];
    __shared__ int totals[16];
    const int tid = threadIdx.x;
    const int ak = akPtr[0];
    const int cap = 384 * ak;   // floor(4096*1.5*ak/16)
    int c[16];
#pragma unroll
    for (int e = 0; e < 16; ++e) c[e] = 0;
    const int n0 = tid * 32;
    for (int j = 0; j < 32; ++j) {
        const int n = n0 + j;
        if ((n & 1) < ak) c[topkI[n]]++;
    }
#pragma unroll
    for (int e = 0; e < 16; ++e) cnt[tid][e] = c[e];
    __syncthreads();
    if (tid < 16) {   // exclusive scan over the 256 chunks, per expert
        int run = 0;
        for (int i = 0; i < 256; ++i) { const int v = cnt[i][tid]; cnt[i][tid] = run; run += v; }
        totals[tid] = run;
    }
    __syncthreads();
#pragma unroll
    for (int e = 0; e < 16; ++e) c[e] = cnt[tid][e];
    for (int j = 0; j < 32; ++j) {
        const int n = n0 + j;
        const int k = n & 1;
        if (k < ak) {
            const int e = topkI[n];
            const int pos = c[e]++;
            if (pos < cap) {
                const int t = n >> 1;
                const float p0 = topkP[t * 2], p1 = topkP[t * 2 + 1];
                const float ssum = (ak == 2) ? (p0 + p1) : p0;
                const float pv = ((k == 0) ? p0 : p1) / (ssum + 1e-8f);
                const float iw = (imp[t] > 0.5f) ? 2.f : 1.f;
                const size_t idx = (size_t)t * (NEXP * CAPM) + (size_t)e * CAPM + pos;
                disp[idx] = 1.f;
                comb[idx] = pv * iw;
            }
        }
    }
    if (tid == 0) {
        float a = 0.f;
        const float invAk = 1.f / (float)(TOK * ak);
        for (int e = 0; e < 16; ++e)
            a += (probsum[e] * (1.f / TOK)) * ((float)totals[e] * invAk);
        aux[0] = a * (float)NEXP;
    }
}

extern "C" void kernel_launch(void* const* d_in, const int* in_sizes, int n_in,
                              void* d_out, int out_size, void* d_ws, size_t ws_size,
                              hipStream_t stream)
{
    const float* x   = (const float*)d_in[0];
    const float* W1  = (const float*)d_in[1];
    const float* b1  = (const float*)d_in[2];
    const float* W2  = (const float*)d_in[3];
    const float* b2  = (const float*)d_in[4];
    const float* Wi1 = (const float*)d_in[5];
    const float* bi1 = (const float*)d_in[6];
    const float* Wi2 = (const float*)d_in[7];
    const float* bi2 = (const float*)d_in[8];
    const float* Wt1 = (const float*)d_in[9];
    const float* bt1 = (const float*)d_in[10];
    const float* Wt2 = (const float*)d_in[11];
    const float* bt2 = (const float*)d_in[12];
    (void)in_sizes; (void)n_in; (void)out_size; (void)ws_size;

    float* out = (float*)d_out;
    float* wsF = (float*)d_ws;
    int*   akP = (int*)(wsF + WS_AK);

    // zero the atomic accumulators (ws is poisoned each call)
    hipMemsetAsync(d_ws, 0, (size_t)WS_ZEROF * 4, stream);

    // h1 intermediate lives in the dispatch region (zeroed later, before scatter)
    float* h1scratch = out + DISP_OFF;

    kA  <<<dim3(12, 64), 256, 0, stream>>>(x, W1, b1, Wi1, bi1, Wi2,
                                           h1scratch, wsF + WS_IMPZ);
    kSig<<<16, 256, 0, stream>>>(wsF + WS_IMPZ, bi2, out + IMP_OFF);
    kAvg<<<dim3(4, 64), 256, 0, stream>>>(x, wsF + WS_COLSUM);
    kTk1<<<32, 256, 0, stream>>>(wsF + WS_COLSUM, Wt1, wsF + WS_T1PRE);
    kTk2<<<1, 256, 0, stream>>>(out + IMP_OFF, wsF + WS_T1PRE, Wt1, bt1, Wt2, bt2, akP);
    kLog<<<256, 256, 0, stream>>>(h1scratch, W2, b2, out + RP_OFF,
                                  wsF + WS_TOPKP, (int*)(wsF + WS_TOPKI), wsF + WS_PROBS);
    // zero dispatch + combine (402,653,184 bytes) AFTER h1 is consumed
    hipMemsetAsync(out, 0, (size_t)COMB_OFF * 2 * sizeof(float), stream);
    kScan<<<1, 256, 0, stream>>>(wsF + WS_TOPKP, (int*)(wsF + WS_TOPKI), akP,
                                 wsF + WS_PROBS, out + IMP_OFF,
                                 out + DISP_OFF, out + COMB_OFF, out + AUX_OFF);
}